// Round 4
// baseline (94.407 us; speedup 1.0000x reference)
//
#include <hip/hip_runtime.h>

// HybridSparseIndexGen3D: for each row i in [0, L), L = t*h*w + 2, emit the
// ascending list of selected ext-columns:
//   col 0 (sentinel), {j+1 : mask[i][j]}, col L-1 (sentinel), zero-padded to K.
// mask[i][j] = local (all |d| <= 2)  OR  sparse (exactly one axis |d| in
// {1,2,4}, others 0). Sparse offsets 1,2 lie inside the local window, so only
// |d|==4 single-axis points add beyond local. Enumerating jt->jh->jw ascending
// gives the sorted order directly (j = (jt*h + jh)*w + jw is lexicographic).
//
// OUTPUT DTYPE IS INT32 (reference returns int32/bool/int32; harness reads
// d_out as int32 and casts to float for comparison). Round-1 failure was
// writing IEEE float bit patterns here (absmax 1.1744e9 == bits of 8189.0f).
// Rounds 2-3 were infra failures (GPU timeout / container), so this is the
// same int32 source resubmitted, still unvalidated on HW.
//
// Output layout (all int32): [idx: L*K][valid: L*K][coords: L*3].
// K is derived on-device from out_size = L*(2K+3).

__global__ void hybrid_sparse_idx_kernel(const int* __restrict__ pt,
                                         const int* __restrict__ ph,
                                         const int* __restrict__ pw,
                                         int* __restrict__ out,
                                         int out_size) {
    const int t = pt[0], h = ph[0], w = pw[0];
    const int hw = h * w;
    const int N = t * hw;
    const int L = N + 2;
    const int K = (out_size / L - 3) / 2;

    int* __restrict__ out_idx   = out;
    int* __restrict__ out_valid = out + (size_t)L * K;
    int* __restrict__ out_crd   = out + (size_t)2 * L * K;

    for (int i = blockIdx.x * blockDim.x + threadIdx.x; i < L;
         i += gridDim.x * blockDim.x) {
        // --- row coordinates (all_coords[i]) ---
        int at, ah, aw;
        if (i == 0)          { at = -1; ah = -1; aw = -1; }
        else if (i == L - 1) { at = t;  ah = h;  aw = w;  }
        else {
            int j = i - 1;
            at = j / hw;
            int r = j - at * hw;
            ah = r / w;
            aw = r - ah * w;
        }
        out_crd[3 * i + 0] = at;
        out_crd[3 * i + 1] = ah;
        out_crd[3 * i + 2] = aw;

        int* ridx = out_idx   + (size_t)i * K;
        int* rval = out_valid + (size_t)i * K;

        int pos = 0;
        // leading sentinel column 0 (always selected)
        ridx[0] = 0; rval[0] = 1; pos = 1;

        // sparse-along-t emission needs jh==ah, jw==aw to be valid patch coords
        const bool hw_ok = (ah >= 0) && (ah < h) && (aw >= 0) && (aw < w);
        const bool w_ok  = (aw >= 0) && (aw < w);

        int jt0 = at - 4; if (jt0 < 0) jt0 = 0;
        int jt1 = at + 4; if (jt1 > t - 1) jt1 = t - 1;
        for (int jt = jt0; jt <= jt1; ++jt) {
            const int adt = abs(jt - at);
            if (adt > 2) {
                // only sparse-t possible: |dt|==4, dh==dw==0
                if (adt == 4 && hw_ok) {
                    const int j = (jt * h + ah) * w + aw;
                    if (pos < K) { ridx[pos] = j + 1; rval[pos] = 1; }
                    ++pos;
                }
                continue;
            }
            int jh0 = ah - 4; if (jh0 < 0) jh0 = 0;
            int jh1 = ah + 4; if (jh1 > h - 1) jh1 = h - 1;
            for (int jh = jh0; jh <= jh1; ++jh) {
                const int adh = abs(jh - ah);
                if (adh > 2) {
                    // only sparse-h possible: |dh|==4, dt==dw==0
                    if (adh == 4 && adt == 0 && w_ok) {
                        const int j = (jt * h + jh) * w + aw;
                        if (pos < K) { ridx[pos] = j + 1; rval[pos] = 1; }
                        ++pos;
                    }
                    continue;
                }
                int jw0 = aw - 4; if (jw0 < 0) jw0 = 0;
                int jw1 = aw + 4; if (jw1 > w - 1) jw1 = w - 1;
                for (int jw = jw0; jw <= jw1; ++jw) {
                    const int adw = abs(jw - aw);
                    // local window OR sparse-w (|dw|==4, dt==dh==0)
                    const bool keep =
                        (adw <= 2) || (adw == 4 && adt == 0 && adh == 0);
                    if (keep) {
                        const int j = (jt * h + jh) * w + jw;
                        if (pos < K) { ridx[pos] = j + 1; rval[pos] = 1; }
                        ++pos;
                    }
                }
            }
        }

        // trailing sentinel column L-1 (always selected)
        if (pos < K) { ridx[pos] = L - 1; rval[pos] = 1; }
        ++pos;

        // zero-pad the remainder (harness poisons d_out, so every element
        // must be written)
        for (int k = pos; k < K; ++k) { ridx[k] = 0; rval[k] = 0; }
    }
}

extern "C" void kernel_launch(void* const* d_in, const int* in_sizes, int n_in,
                              void* d_out, int out_size, void* d_ws, size_t ws_size,
                              hipStream_t stream) {
    (void)in_sizes; (void)n_in; (void)d_ws; (void)ws_size;
    const int* pt = (const int*)d_in[0];
    const int* ph = (const int*)d_in[1];
    const int* pw = (const int*)d_in[2];
    int* out = (int*)d_out;

    // t=8, h=32, w=32 -> L = 8194 rows; grid-stride loop keeps it correct for
    // any dims. 129 blocks x 64 threads ~= one wave per row-chunk.
    const int block = 64;
    const int grid  = 129;
    hybrid_sparse_idx_kernel<<<grid, block, 0, stream>>>(pt, ph, pw, out, out_size);
}

// Round 5
// 69.701 us; speedup vs baseline: 1.3544x; 1.3544x over previous
//
#include <hip/hip_runtime.h>

// HybridSparseIndexGen3D — wave-per-row ballot-compaction version.
//
// For each row i in [0, L), L = t*h*w + 2, emit ascending selected ext-cols:
//   col 0 (sentinel), {j+1 : mask[i][j]}, col L-1 (sentinel), zero-pad to K.
// mask = local (all |d|<=2) OR sparse (exactly one axis |d| in {1,2,4}, others
// 0). Sparse 1,2 lie inside the window => only single-axis |d|==4 adds.
// All candidates live in the 9^3 box [c-4, c+4]^3; enumerating the box in
// lexicographic (jt,jh,jw) order gives ascending j = (jt*h+jh)*w+jw directly.
//
// Round-4 evidence: kernel passed (absmax 0); top-5 dispatches are the
// harness's 256 MiB d_ws poison fills (~41us each) — our kernel < 41us,
// est. ~10us of the 94.4us total. Bottleneck was 129 waves total (no TLP) +
// ~275-iter serial divergent loop + scattered stores (adjacent lanes 528B
// apart). This version: ONE WAVE PER ROW (8194 waves = 32 waves/CU), lanes
// cover the 729-candidate box in 12 ballot iterations; __ballot+popcount
// prefix preserves lex order and makes kept-lane stores consecutive
// (coalesced).
//
// OUTPUT DTYPE INT32 (harness reads d_out as int32 -> float for compare).
// Layout: [idx: L*K][valid: L*K][coords: L*3]; K from out_size = L*(2K+3).

__global__ __launch_bounds__(256) void hybrid_sparse_idx_wave(
        const int* __restrict__ pt, const int* __restrict__ ph,
        const int* __restrict__ pw, int* __restrict__ out, int out_size) {
    const int t = pt[0], h = ph[0], w = pw[0];
    const int hw = h * w;
    const int N = t * hw;
    const int L = N + 2;
    const int K = (out_size / L - 3) / 2;

    int* __restrict__ out_idx   = out;
    int* __restrict__ out_valid = out + (size_t)L * K;
    int* __restrict__ out_crd   = out + (size_t)2 * L * K;

    const int lane    = threadIdx.x & 63;
    const int wave    = threadIdx.x >> 6;          // 4 waves per 256-thr block
    const int wperblk = blockDim.x >> 6;
    const unsigned long long lanemask_lt = (1ull << lane) - 1ull;

    for (int i = blockIdx.x * wperblk + wave; i < L;
         i += gridDim.x * wperblk) {
        // --- row coordinate (all_coords[i]) ---
        int at, ah, aw;
        if (i == 0)          { at = -1; ah = -1; aw = -1; }
        else if (i == L - 1) { at = t;  ah = h;  aw = w;  }
        else {
            int j = i - 1;
            at = j / hw;
            int r = j - at * hw;
            ah = r / w;
            aw = r - ah * w;
        }
        if (lane < 3) {
            int v = (lane == 0) ? at : ((lane == 1) ? ah : aw);
            out_crd[3 * i + lane] = v;
        }

        int* ridx = out_idx   + (size_t)i * K;
        int* rval = out_valid + (size_t)i * K;

        // position 0: leading sentinel (column 0)
        if (lane == 0) { ridx[0] = 0; rval[0] = 1; }
        int pos = 1;

        // 729 candidates in lex order, 64 lanes at a time (12 iterations)
        for (int base = 0; base < 729; base += 64) {
            const int c = base + lane;
            bool keep = false;
            int  j    = 0;
            if (c < 729) {
                const int ot = c / 81;          // 0..8
                const int rc = c - ot * 81;
                const int oh = rc / 9;          // 0..8
                const int ow = rc - oh * 9;     // 0..8
                const int jt = at - 4 + ot;
                const int jh = ah - 4 + oh;
                const int jw = aw - 4 + ow;
                if (jt >= 0 && jt < t && jh >= 0 && jh < h &&
                    jw >= 0 && jw < w) {
                    const int adt = ot >= 4 ? ot - 4 : 4 - ot;  // |jt-at|
                    const int adh = oh >= 4 ? oh - 4 : 4 - oh;
                    const int adw = ow >= 4 ? ow - 4 : 4 - ow;
                    const bool local  = (adt <= 2) & (adh <= 2) & (adw <= 2);
                    const bool sparse =
                        ((adt == 4) & (adh == 0) & (adw == 0)) |
                        ((adh == 4) & (adt == 0) & (adw == 0)) |
                        ((adw == 4) & (adt == 0) & (adh == 0));
                    keep = local | sparse;
                    j = (jt * h + jh) * w + jw;
                }
            }
            const unsigned long long ball = __ballot(keep);
            if (keep) {
                const int p = pos + __popcll(ball & lanemask_lt);
                if (p < K) { ridx[p] = j + 1; rval[p] = 1; }
            }
            pos += __popcll(ball);
        }

        // trailing sentinel (column L-1); j+1 <= N < L-1, so never duplicated
        if (lane == 0 && pos < K) { ridx[pos] = L - 1; rval[pos] = 1; }
        ++pos;  // pos == counts[i]

        // zero-pad [pos, K) — harness poisons d_out, every element must be
        // written
        for (int k = pos + lane; k < K; k += 64) { ridx[k] = 0; rval[k] = 0; }
    }
}

extern "C" void kernel_launch(void* const* d_in, const int* in_sizes, int n_in,
                              void* d_out, int out_size, void* d_ws, size_t ws_size,
                              hipStream_t stream) {
    (void)in_sizes; (void)n_in; (void)d_ws; (void)ws_size;
    const int* pt = (const int*)d_in[0];
    const int* ph = (const int*)d_in[1];
    const int* pw = (const int*)d_in[2];
    int* out = (int*)d_out;

    // t=8,h=32,w=32 -> L=8194 rows; 4 waves/block -> 2049 blocks = 8 blocks/CU
    // (32 waves/CU, full occupancy). Grid-stride keeps it correct generally.
    const int block = 256;
    const int rows_per_block = block / 64;
    const int grid = 2049;  // covers L=8194 at 4 rows/block; loop handles rest
    hybrid_sparse_idx_wave<<<grid, block, 0, stream>>>(pt, ph, pw, out,
                                                       out_size);
    (void)rows_per_block;
}

// Round 6
// 65.532 us; speedup vs baseline: 1.4406x; 1.0636x over previous
//
#include <hip/hip_runtime.h>

// HybridSparseIndexGen3D — wave-per-row, LDS-compaction + wide-store version.
//
// Per row i in [0, L), L = t*h*w + 2: emit ascending selected ext-columns
//   [0 (sentinel), {j+1 : mask[i][j]}, L-1 (sentinel)], zero-padded to K.
// mask = local (all |d|<=2) OR sparse (one axis |d| in {1,2,4}, others 0);
// sparse 1,2 are inside the window so only single-axis |d|==4 adds. All
// candidates live in the 9^3=729 box [c-4,c+4]^3; lexicographic box order
// == ascending j. keep-pattern (local|sparse as a function of box offset) is
// ROW-INDEPENDENT -> 12 constexpr 64-bit masks; per-lane work is bounds only.
//
// Round-4 (serial/thread): kernel >= 25us. Round-5 (wave-per-row, 24 masked
// scattered stores/row): dur 69.7us total, kernel <= ~26us. This version:
// compact kept j+1 into a per-wave LDS row (consecutive -> conflict-free),
// then ONE 33-lane global_store_dwordx4 for the whole idx row; valid row is
// simply (k < counts) -> one more dwordx4; no LDS needed for it.
//
// OUTPUT DTYPE INT32. Layout: [idx: L*K][valid: L*K][coords: L*3];
// K = (out_size/L - 3)/2. Max possible K = 125 + 6 + 2 = 133 <= 136 (LDS row).

struct Masks {
    unsigned long long keep[12];
};

constexpr Masks make_masks() {
    Masks m{};
    for (int i = 0; i < 12; ++i) m.keep[i] = 0ull;
    for (int c = 0; c < 729; ++c) {
        const int ot = c / 81;
        const int oh = (c % 81) / 9;
        const int ow = c % 9;
        const int adt = ot >= 4 ? ot - 4 : 4 - ot;
        const int adh = oh >= 4 ? oh - 4 : 4 - oh;
        const int adw = ow >= 4 ? ow - 4 : 4 - ow;
        const bool local = (adt <= 2) && (adh <= 2) && (adw <= 2);
        const bool sparse =
            ((adt == 4) && (adh == 0) && (adw == 0)) ||
            ((adh == 4) && (adt == 0) && (adw == 0)) ||
            ((adw == 4) && (adt == 0) && (adh == 0));
        if (local || sparse) m.keep[c >> 6] |= (1ull << (c & 63));
    }
    return m;
}

__global__ __launch_bounds__(256) void hybrid_sparse_idx_lds(
        const int* __restrict__ pt, const int* __restrict__ ph,
        const int* __restrict__ pw, int* __restrict__ out, int out_size) {
    constexpr Masks M = make_masks();
    __shared__ int slds[4][136];  // one 136-int row buffer per wave

    const int t = pt[0], h = ph[0], w = pw[0];
    const int hw = h * w;
    const int N = t * hw;
    const int L = N + 2;
    const int K = (out_size / L - 3) / 2;

    int* __restrict__ out_idx = out;
    int* __restrict__ out_val = out + (size_t)L * K;
    int* __restrict__ out_crd = out + (size_t)2 * L * K;

    const int lane = threadIdx.x & 63;
    const int wv   = threadIdx.x >> 6;  // 4 waves / block, one row each
    const unsigned long long lt = (1ull << lane) - 1ull;
    int* __restrict__ my = slds[wv];

    // Single-pass for t=8,h=32,w=32 (grid 2049*4 >= L); loop keeps it correct
    // for other dims. No block-level barriers anywhere -> early-exit safe.
    for (int i = blockIdx.x * 4 + wv; i < L; i += gridDim.x * 4) {
        int at, ah, aw;
        if (i == 0)          { at = -1; ah = -1; aw = -1; }
        else if (i == L - 1) { at = t;  ah = h;  aw = w;  }
        else {
            const int j = i - 1;
            at = j / hw;
            const int r = j - at * hw;
            ah = r / w;
            aw = r - ah * w;
        }
        if (lane < 3)
            out_crd[3 * i + lane] = (lane == 0) ? at : ((lane == 1) ? ah : aw);

        if (lane == 0) my[0] = 0;  // leading sentinel (column 0)
        int pos = 1;

        // 729 candidates, 64 lanes x 12 chunks, lexicographic order
#pragma unroll
        for (int chunk = 0; chunk < 12; ++chunk) {
            const unsigned c = chunk * 64u + (unsigned)lane;
            const bool pat = (M.keep[chunk] >> lane) & 1ull;
            const unsigned ot = c / 81u;
            const unsigned rc = c - ot * 81u;
            const unsigned oh = rc / 9u;
            const unsigned ow = rc - oh * 9u;
            const int jt = at - 4 + (int)ot;
            const int jh = ah - 4 + (int)oh;
            const int jw = aw - 4 + (int)ow;
            const bool inb = ((unsigned)jt < (unsigned)t) &
                             ((unsigned)jh < (unsigned)h) &
                             ((unsigned)jw < (unsigned)w);
            const bool keepv = pat & inb;
            const unsigned long long ball = __ballot(keepv);
            if (keepv)
                my[pos + __popcll(ball & lt)] = (jt * h + jh) * w + jw + 1;
            pos += __popcll(ball);
        }

        if (lane == 0) my[pos] = L - 1;  // trailing sentinel
        const int cnt = pos + 1;         // == counts[i]

        // zero LDS tail so the vector readback covers [cnt, K)
        const int K4 = (K + 3) & ~3;
        for (int k = cnt + lane; k < K4; k += 64) my[k] = 0;

        // per-wave LDS write->read ordering (no block barrier needed)
        asm volatile("s_waitcnt lgkmcnt(0)" ::: "memory");

        const int nvec = K >> 2;   // 33 for K=132
        const int rem  = K & 3;    // 0 for K=132
        // idx row: one dwordx4 store (row base i*K*4 is 16B-aligned for K%4==0)
        if (lane < nvec) {
            const int b = lane << 2;
            const int4 v = *reinterpret_cast<const int4*>(&my[b]);
            *reinterpret_cast<int4*>(&out_idx[(size_t)i * K + b]) = v;
        }
        if (lane < rem)
            out_idx[(size_t)i * K + (nvec << 2) + lane] = my[(nvec << 2) + lane];

        // valid row: val[k] = (k < cnt), no staging needed
        if (lane < nvec) {
            const int b = lane << 2;
            int4 v;
            v.x = (b + 0) < cnt;
            v.y = (b + 1) < cnt;
            v.z = (b + 2) < cnt;
            v.w = (b + 3) < cnt;
            *reinterpret_cast<int4*>(&out_val[(size_t)i * K + b]) = v;
        }
        if (lane < rem) {
            const int k = (nvec << 2) + lane;
            out_val[(size_t)i * K + k] = (k < cnt) ? 1 : 0;
        }
    }
}

extern "C" void kernel_launch(void* const* d_in, const int* in_sizes, int n_in,
                              void* d_out, int out_size, void* d_ws, size_t ws_size,
                              hipStream_t stream) {
    (void)in_sizes; (void)n_in; (void)d_ws; (void)ws_size;
    const int* pt = (const int*)d_in[0];
    const int* ph = (const int*)d_in[1];
    const int* pw = (const int*)d_in[2];
    int* out = (int*)d_out;

    // t=8,h=32,w=32 -> L=8194 rows; 2049 blocks x 4 waves = 8196 wave-slots,
    // single pass, 32 waves/CU-class occupancy. Grid-stride loop for other dims.
    const int block = 256;
    const int grid  = 2049;
    hybrid_sparse_idx_lds<<<grid, block, 0, stream>>>(pt, ph, pw, out, out_size);
}